// Round 3
// baseline (215.384 us; speedup 1.0000x reference)
//
#include <hip/hip_runtime.h>

#define C 128
#define H 128
#define W 128
#define HW (H*W)

// Fully fused: corr(25 dilated taps) + g(=feat·w_cls at tap rows) + relu
// + softmax + gather + bias, one pass over feat.
// block = (b, output row r); 512 thr = 8 waves x 16 channels; lane owns 2 px.
__global__ __launch_bounds__(512, 4) void fused_kernel(
    const float* __restrict__ feat, const float* __restrict__ wc,
    const float* __restrict__ bc, float* __restrict__ out)
{
    __shared__ float corr_s[25][W];   // [tap][col]
    __shared__ float g_s[5][W];       // [tap-row][col]
    __shared__ float wc_s[C];

    const int blk  = blockIdx.x;      // b*H + r
    const int b    = blk >> 7;
    const int r    = blk & 127;
    const int tid  = threadIdx.x;
    const int wv   = tid >> 6;        // wave = channel group (16 ch)
    const int lane = tid & 63;
    const int w0   = lane * 2;        // lane owns cols w0, w0+1

    for (int i = tid; i < 25 * W; i += 512) (&corr_s[0][0])[i] = 0.f;
    for (int i = tid; i < 5 * W;  i += 512) (&g_s[0][0])[i]  = 0.f;
    if (tid < C) wc_s[tid] = wc[tid];
    __syncthreads();

    // tap-row offsets (clamped) + validity (block-uniform)
    int roff[5]; bool rokv[5];
#pragma unroll
    for (int i = 0; i < 5; ++i) {
        const int rt = r - 4 + 2 * i;
        rokv[i] = ((unsigned)rt < (unsigned)H);
        const int rc = rt < 0 ? 0 : (rt > H - 1 ? H - 1 : rt);
        roff[i] = rc * W;
    }
    // tap-col base offsets, clamped to even (float2-aligned). Whenever a
    // clamp fires, BOTH px's taps at that j are OOB -> masked later.
    int coff[5];
#pragma unroll
    for (int j = 0; j < 5; ++j) {
        const int cs = w0 - 4 + 2 * j;
        coff[j] = cs < 0 ? 0 : (cs > W - 2 ? W - 2 : cs);
    }

    const float* fb = feat + ((size_t)(b * C + wv * 16)) * HW;

    float acc[25][2], gacc[5][2];
#pragma unroll
    for (int n = 0; n < 25; ++n) { acc[n][0] = 0.f; acc[n][1] = 0.f; }
#pragma unroll
    for (int i = 0; i < 5; ++i)  { gacc[i][0] = 0.f; gacc[i][1] = 0.f; }

#pragma unroll 1
    for (int c = 0; c < 16; ++c) {
        const float* fp = fb + (size_t)c * HW;
        const float wcv = wc_s[wv * 16 + c];

        // center row first (provides ctr), then the other 4 tap rows
        float2 row2[5];
#pragma unroll
        for (int j = 0; j < 5; ++j) row2[j] = *(const float2*)(fp + roff[2] + coff[j]);
        const float2 ctr = row2[2];   // own px values (col w0, w0+1), never clamped
        gacc[2][0] = fmaf(wcv, ctr.x, gacc[2][0]);
        gacc[2][1] = fmaf(wcv, ctr.y, gacc[2][1]);
#pragma unroll
        for (int j = 0; j < 5; ++j) {
            acc[10 + j][0] = fmaf(ctr.x, row2[j].x, acc[10 + j][0]);
            acc[10 + j][1] = fmaf(ctr.y, row2[j].y, acc[10 + j][1]);
        }
#pragma unroll
        for (int i = 0; i < 5; ++i) {
            if (i == 2) continue;
            float2 rv[5];
#pragma unroll
            for (int j = 0; j < 5; ++j) rv[j] = *(const float2*)(fp + roff[i] + coff[j]);
            gacc[i][0] = fmaf(wcv, rv[2].x, gacc[i][0]);
            gacc[i][1] = fmaf(wcv, rv[2].y, gacc[i][1]);
#pragma unroll
            for (int j = 0; j < 5; ++j) {
                acc[i * 5 + j][0] = fmaf(ctr.x, rv[j].x, acc[i * 5 + j][0]);
                acc[i * 5 + j][1] = fmaf(ctr.y, rv[j].y, acc[i * 5 + j][1]);
            }
        }
    }

    // mask OOB taps once, reduce across the 8 waves
#pragma unroll
    for (int i = 0; i < 5; ++i)
#pragma unroll
        for (int j = 0; j < 5; ++j) {
            const int n  = i * 5 + j;
            const int cs = w0 - 4 + 2 * j;
            const float v0 = (rokv[i] && ((unsigned)cs       < (unsigned)W)) ? acc[n][0] : 0.f;
            const float v1 = (rokv[i] && ((unsigned)(cs + 1) < (unsigned)W)) ? acc[n][1] : 0.f;
            atomicAdd(&corr_s[n][w0],     v0);
            atomicAdd(&corr_s[n][w0 + 1], v1);
        }
#pragma unroll
    for (int i = 0; i < 5; ++i) {
        atomicAdd(&g_s[i][w0],     gacc[i][0]);
        atomicAdd(&g_s[i][w0 + 1], gacc[i][1]);
    }
    __syncthreads();

    if (tid < W) {
        const int w = tid;
        float v[25], m = 0.f;
#pragma unroll
        for (int n = 0; n < 25; ++n) {
            v[n] = fmaxf(corr_s[n][w], 0.f);
            m = fmaxf(m, v[n]);
        }
        float s = 0.f, num = 0.f;
#pragma unroll
        for (int i = 0; i < 5; ++i)
#pragma unroll
            for (int j = 0; j < 5; ++j) {
                const float e = __expf(v[i * 5 + j] - m);
                s += e;
                const int wt = w - 4 + 2 * j;
                const float gv = (rokv[i] && ((unsigned)wt < (unsigned)W)) ? g_s[i][wt] : 0.f;
                num = fmaf(e, gv, num);
            }
        out[(size_t)blk * W + w] = num / s + bc[0];
    }
}

extern "C" void kernel_launch(void* const* d_in, const int* in_sizes, int n_in,
                              void* d_out, int out_size, void* d_ws, size_t ws_size,
                              hipStream_t stream) {
    const float* feat = (const float*)d_in[0];
    const float* wcls = (const float*)d_in[1];
    const float* bcls = (const float*)d_in[2];
    float* outp = (float*)d_out;

    fused_kernel<<<dim3(4 * H), dim3(512), 0, stream>>>(feat, wcls, bcls, outp);
}

// Round 4
// 132.973 us; speedup vs baseline: 1.6198x; 1.6198x over previous
//
#include <hip/hip_runtime.h>

#define C 128
#define H 128
#define W 128
#define HW (H*W)

// Fully fused feature-propagate + 1x1 classifier (num_classes=1).
// block = (b, output row r), 640 thr = 10 waves = (tap-row i in 0..4) x (ch-half).
// Wave (i,half): for its 64 channels, loads tap row rt=r-4+2i window + center row,
// accumulates corr partials for taps (i,0..4) and g partial for row rt.
// LDS: disjoint per-wave slices -> plain writes, no atomics.
__global__ __launch_bounds__(640, 4) void fused_kernel(
    const float* __restrict__ feat, const float* __restrict__ wc,
    const float* __restrict__ bc, float* __restrict__ out)
{
    __shared__ float corr_s[2][25][W];   // [ch-half][tap][col]
    __shared__ float g_s[2][5][W];       // [ch-half][tap-row][col]

    const int blk0 = blockIdx.x;
    const int blk  = (blk0 & 7) * 64 + (blk0 >> 3);   // XCD swizzle (512 = 8*64, bijective)
    const int b    = blk >> 7;
    const int r    = blk & 127;
    const int tid  = threadIdx.x;
    const int wv   = tid >> 6;           // 0..9
    const int ti   = wv >> 1;            // tap row index 0..4
    const int half = wv & 1;             // channel half (64 ch)
    const int lane = tid & 63;
    const int w0   = lane * 2;           // lane owns cols w0, w0+1

    const int rt   = r - 4 + 2 * ti;     // this wave's tap row (wave-uniform)
    const bool rok = (unsigned)rt < (unsigned)H;

    float acc[5][2];                     // corr partials for taps (ti, j)
    float ga0 = 0.f, ga1 = 0.f;          // g partial for tap row rt
#pragma unroll
    for (int j = 0; j < 5; ++j) { acc[j][0] = 0.f; acc[j][1] = 0.f; }

    if (rok) {                           // wave-uniform branch
        // clamped float2-aligned col offsets for the 5 j-taps
        int coff[5];
#pragma unroll
        for (int j = 0; j < 5; ++j) {
            const int cs = w0 - 4 + 2 * j;
            coff[j] = cs < 0 ? 0 : (cs > W - 2 ? W - 2 : cs);
        }
        const float* fp = feat + ((size_t)(b * C + half * 64)) * HW + rt * W;
        const float* cp = feat + ((size_t)(b * C + half * 64)) * HW + r  * W + w0;
#pragma unroll 2
        for (int c = 0; c < 64; ++c) {
            const float2 ctr = *(const float2*)cp;          // center px pair
            const float  wcv = wc[half * 64 + c];           // uniform -> s_load
            float2 t[5];
#pragma unroll
            for (int j = 0; j < 5; ++j) t[j] = *(const float2*)(fp + coff[j]);
            ga0 = fmaf(wcv, t[2].x, ga0);                   // j=2 tap col == own col
            ga1 = fmaf(wcv, t[2].y, ga1);
#pragma unroll
            for (int j = 0; j < 5; ++j) {
                acc[j][0] = fmaf(ctr.x, t[j].x, acc[j][0]);
                acc[j][1] = fmaf(ctr.y, t[j].y, acc[j][1]);
            }
            fp += HW; cp += HW;
        }
    }

    // masked disjoint writes (clamped-load garbage & invalid rows -> exact 0)
#pragma unroll
    for (int j = 0; j < 5; ++j) {
        const int  cs = w0 - 4 + 2 * j;
        const bool ok = rok && ((unsigned)cs < 127u);       // valid for both px
        corr_s[half][ti * 5 + j][w0]     = ok ? acc[j][0] : 0.f;
        corr_s[half][ti * 5 + j][w0 + 1] = ok ? acc[j][1] : 0.f;
    }
    g_s[half][ti][w0]     = ga0;   // rok==false -> zeros, matches zero-pad
    g_s[half][ti][w0 + 1] = ga1;
    __syncthreads();

    // relu -> softmax over 25 taps -> sum attn * g -> + bias
    if (tid < W) {
        const int w = tid;
        float v[25], m = 0.f;
#pragma unroll
        for (int n = 0; n < 25; ++n) {
            v[n] = fmaxf(corr_s[0][n][w] + corr_s[1][n][w], 0.f);
            m = fmaxf(m, v[n]);
        }
        float s = 0.f, num = 0.f;
#pragma unroll
        for (int i = 0; i < 5; ++i)
#pragma unroll
            for (int j = 0; j < 5; ++j) {
                const float e = __expf(v[i * 5 + j] - m);
                s += e;
                const int  wt = w - 4 + 2 * j;
                const bool ok = (unsigned)wt < (unsigned)W;
                const int  wi = ok ? wt : 0;
                const float gv = g_s[0][i][wi] + g_s[1][i][wi];
                num = fmaf(e, ok ? gv : 0.f, num);
            }
        out[((size_t)(b * H + r)) * W + w] = num / s + bc[0];
    }
}

extern "C" void kernel_launch(void* const* d_in, const int* in_sizes, int n_in,
                              void* d_out, int out_size, void* d_ws, size_t ws_size,
                              hipStream_t stream) {
    const float* feat = (const float*)d_in[0];
    const float* wcls = (const float*)d_in[1];
    const float* bcls = (const float*)d_in[2];
    float* outp = (float*)d_out;

    fused_kernel<<<dim3(4 * H), dim3(640), 0, stream>>>(feat, wcls, bcls, outp);
}

// Round 5
// 94.340 us; speedup vs baseline: 2.2831x; 1.4095x over previous
//
#include <hip/hip_runtime.h>

#define C 128
#define H 128
#define W 128
#define HW (H*W)

// Fused feature-propagate + 1x1 classifier (num_classes=1), one pass over feat.
// block = (b, output row r), 640 thr = 10 waves = (tap-row i in 0..4) x (ch-half h).
// lane: s = lane>>5 picks a 32-channel sub-half, pg = lane&31 picks 4 px (float4).
// Per channel-iter: 3 clamped window float4 + 1 center float4 -> 24 FMAs.
__global__ __launch_bounds__(640, 4) void fused_kernel(
    const float* __restrict__ feat, const float* __restrict__ wc,
    const float* __restrict__ bc, float* __restrict__ out)
{
    __shared__ float corr_s[2][25][W];   // [ch-half][tap][col]
    __shared__ float g_s[2][5][W];       // [ch-half][tap-row][col]
    __shared__ float wc_s[C];

    const int blk0 = blockIdx.x;
    const int blk  = (blk0 & 7) * 64 + (blk0 >> 3);   // XCD swizzle (512 = 8*64)
    const int b    = blk >> 7;
    const int r    = blk & 127;
    const int tid  = threadIdx.x;
    const int wv   = tid >> 6;           // 0..9
    const int ti   = wv >> 1;            // tap-row index 0..4
    const int h    = wv & 1;             // 64-channel half
    const int lane = tid & 63;
    const int s    = lane >> 5;          // 32-channel sub-half
    const int pg   = lane & 31;
    const int w0   = pg * 4;             // lane owns cols w0..w0+3

    if (tid < C) wc_s[tid] = wc[tid];
    __syncthreads();

    const int  rt  = r - 4 + 2 * ti;     // wave's tap row
    const bool rok = (unsigned)rt < (unsigned)H;

    float acc[5][4];                     // corr partials, taps (ti, j=0..4) x 4 px
    float ga[4];                         // g partial for row rt
#pragma unroll
    for (int j = 0; j < 5; ++j)
#pragma unroll
        for (int p = 0; p < 4; ++p) acc[j][p] = 0.f;
#pragma unroll
    for (int p = 0; p < 4; ++p) ga[p] = 0.f;

    if (rok) {                           // wave-uniform
        // window = floats [w0-4, w0+8) of tap row, as 3 16B-aligned slots.
        // Clamped slot => slot is fully OOB => all its taps masked later.
        int sb[3];
#pragma unroll
        for (int t = 0; t < 3; ++t) {
            const int cs = w0 - 4 + 4 * t;
            sb[t] = cs < 0 ? 0 : (cs > W - 4 ? W - 4 : cs);
        }
        const float* fbase = feat + ((size_t)(b * C + h * 64 + s * 32)) * HW;
        const float* tp = fbase + rt * W;        // tap row
        const float* cp = fbase + r * W + w0;    // center row (own px)
        const int wci = h * 64 + s * 32;

#pragma unroll 2
        for (int c = 0; c < 32; ++c) {
            const float4 A  = *(const float4*)(tp + sb[0]);
            const float4 Bv = *(const float4*)(tp + sb[1]);
            const float4 Cv = *(const float4*)(tp + sb[2]);
            const float4 D  = *(const float4*)cp;
            const float wcv = wc_s[wci + c];

            const float win[12] = {A.x, A.y, A.z, A.w,
                                   Bv.x, Bv.y, Bv.z, Bv.w,
                                   Cv.x, Cv.y, Cv.z, Cv.w};
            const float ctr[4] = {D.x, D.y, D.z, D.w};

#pragma unroll
            for (int p = 0; p < 4; ++p)
                ga[p] = fmaf(wcv, win[4 + p], ga[p]);   // own-col tap of row rt
#pragma unroll
            for (int j = 0; j < 5; ++j)
#pragma unroll
                for (int p = 0; p < 4; ++p)
                    acc[j][p] = fmaf(ctr[p], win[p + 2 * j], acc[j][p]);

            tp += HW; cp += HW;
        }
    }

    // reduce the two 32-channel sub-halves within the wave
#pragma unroll
    for (int j = 0; j < 5; ++j)
#pragma unroll
        for (int p = 0; p < 4; ++p)
            acc[j][p] += __shfl_xor(acc[j][p], 32);
#pragma unroll
    for (int p = 0; p < 4; ++p) ga[p] += __shfl_xor(ga[p], 32);

    // masked disjoint writes (s==0 lanes cover all 128 cols)
    if (s == 0) {
#pragma unroll
        for (int j = 0; j < 5; ++j)
#pragma unroll
            for (int p = 0; p < 4; ++p) {
                const int  col = w0 + p - 4 + 2 * j;
                const bool ok  = rok && ((unsigned)col < (unsigned)W);
                corr_s[h][ti * 5 + j][w0 + p] = ok ? acc[j][p] : 0.f;
            }
#pragma unroll
        for (int p = 0; p < 4; ++p) g_s[h][ti][w0 + p] = ga[p];  // 0 if !rok
    }
    __syncthreads();

    // relu -> softmax over 25 taps -> sum attn * g -> + bias
    if (tid < W) {
        const int w = tid;
        float v[25], m = 0.f;
#pragma unroll
        for (int n = 0; n < 25; ++n) {
            v[n] = fmaxf(corr_s[0][n][w] + corr_s[1][n][w], 0.f);
            m = fmaxf(m, v[n]);
        }
        float sum = 0.f, num = 0.f;
#pragma unroll
        for (int i = 0; i < 5; ++i) {
            const bool riv = (unsigned)(r - 4 + 2 * i) < (unsigned)H;
#pragma unroll
            for (int j = 0; j < 5; ++j) {
                const float e = __expf(v[i * 5 + j] - m);
                sum += e;
                const int  wt = w - 4 + 2 * j;
                const bool ok = riv && ((unsigned)wt < (unsigned)W);
                const int  wi = ok ? wt : 0;
                const float gv = g_s[0][i][wi] + g_s[1][i][wi];
                num = fmaf(e, ok ? gv : 0.f, num);
            }
        }
        out[((size_t)(b * H + r)) * W + w] = num / sum + bc[0];
    }
}

extern "C" void kernel_launch(void* const* d_in, const int* in_sizes, int n_in,
                              void* d_out, int out_size, void* d_ws, size_t ws_size,
                              hipStream_t stream) {
    const float* feat = (const float*)d_in[0];
    const float* wcls = (const float*)d_in[1];
    const float* bcls = (const float*)d_in[2];
    float* outp = (float*)d_out;

    fused_kernel<<<dim3(4 * H), dim3(640), 0, stream>>>(feat, wcls, bcls, outp);
}